// Round 10
// baseline (254.076 us; speedup 1.0000x reference)
//
#include <hip/hip_runtime.h>
#include <hip/hip_bf16.h>

#define NN 16384
#define DD 256

typedef unsigned short u16;
typedef unsigned int u32;
typedef unsigned char u8;
typedef long i64;
typedef __attribute__((ext_vector_type(2))) long i64x2;
typedef __attribute__((ext_vector_type(4))) float f32x4;

// async global->LDS, 16B per lane; LDS dest = wave-uniform base + lane*16
static __device__ __forceinline__ void gload16(const u8* g, u8* l) {
    __builtin_amdgcn_global_load_lds(
        (const __attribute__((address_space(1))) void*)g,
        (__attribute__((address_space(3))) void*)l,
        16, 0, 0);
}

// ---------- kernel 1: convert to fp8 e4m3, PAIR-PACKED + XOR-swizzled ----------
// A8 row r (256 B): logical 16B chunk L = kc*4+q holds k-slices [kc*64+q*8, +8)
// and [kc*64+32+q*8, +8) adjacent (s=0|s=1 halves). Stored at chunk position
// P = (L&8) | ((L&7)^(r&7))  -> 8-lane b128 phase covers a 128B half-row = 32
// banks exactly once (R2's measured-zero pattern).
// B8 row r (256 B = 4 kc-blocks of 64 B): within kc-block, chunk q (s0|s1
// halves) stored at P = q ^ ((r>>1)&3) -> even-m lanes cover banks 0..15 once,
// odd-m banks 16..31 once (64B rows alternate half-lines): zero conflict.
__global__ void prep_kernel(const float* __restrict__ img, const float* __restrict__ txt,
                            u8* __restrict__ A8, u8* __restrict__ B8,
                            float* __restrict__ zbuf /* s_row..s_col */, float* __restrict__ out) {
    int gid = blockIdx.x * 256 + threadIdx.x;          // 0 .. 1048575  (N*D/4)
    float4 va = ((const float4*)img)[gid];
    float4 vb = ((const float4*)txt)[gid];
    const float S = 1.44269504088896f;                  // log2(e) folded into A
    int pa = __builtin_amdgcn_cvt_pk_fp8_f32(va.x * S, va.y * S, 0, false);
    pa     = __builtin_amdgcn_cvt_pk_fp8_f32(va.z * S, va.w * S, pa, true);
    int pb = __builtin_amdgcn_cvt_pk_fp8_f32(vb.x, vb.y, 0, false);
    pb     = __builtin_amdgcn_cvt_pk_fp8_f32(vb.z, vb.w, pb, true);

    const int r  = gid >> 6;
    const int ko = (gid & 63) << 2;     // k-byte offset 0..255, step 4
    const int J  = ko >> 3;             // 8-byte slot 0..31
    const int u  = ko & 7;              // 0 or 4
    const int kc = J >> 3;
    const int s  = (J >> 2) & 1;
    const int qq = J & 3;
    // A address
    {
        const int L  = (kc << 2) | qq;
        const int P  = (L & 8) | ((L & 7) ^ (r & 7));
        *(u32*)(A8 + ((size_t)r << 8) + (P << 4) + (s << 3) + u) = (u32)pa;
    }
    // B address
    {
        const int P  = qq ^ ((r >> 1) & 3);
        *(u32*)(B8 + ((size_t)r << 8) + (kc << 6) + (P << 4) + (s << 3) + u) = (u32)pb;
    }
    if (gid < 32768) zbuf[gid] = 0.0f;
    if (gid == 0) out[0] = 0.0f;
}

// ---------- kernel 2: fused fp8 GEMM + exp2 + row/col sum + diag ----------
// R8 structure EXACTLY (A-once 32 KB, single 8 KB B buffer per kc, 2 barriers
// per kc, 40 KB LDS -> 4 blocks/CU, bi-fast grid, register-only epilogue).
// Single change vs R8: pair-packed layout gives ONE ds_read_b128 per operand
// row per kc (32 b128/tile/wave vs 64 b64), in the R2-proven zero-conflict
// bank walk. Each b128 feeds two MFMAs (s=0 half, s=1 half).
__global__ __launch_bounds__(256, 4) void gemm_lse_kernel(
        const u8* __restrict__ A8, const u8* __restrict__ B8,
        float* __restrict__ s_row, float* __restrict__ s_col,
        float* __restrict__ diag) {
    __shared__ u8 sA[32768];        // 128 rows x 256 B (pre-swizzled)
    __shared__ u8 sB[8192];         // 128 rows x 64 B  (pre-swizzled, per kc)

    const int t = threadIdx.x;
    const int lane = t & 63;
    const int w = t >> 6;
    const int wr = w >> 1, wc = w & 1;
    const int q = lane >> 4, m = lane & 15;
    const int bi = blockIdx.x & 127;            // FAST: resident blocks share B phase
    const int jg = blockIdx.x >> 7;
    const int row0 = bi << 7;

    // ---- stage A panel ONCE: linear 32 KB copy, 8 rounds x 256 lanes x 16 B
    #pragma unroll
    for (int R = 0; R < 8; ++R)
        gload16(A8 + ((size_t)row0 << 8) + (R << 12) + (w << 10) + ((size_t)lane << 4),
                &sA[(R << 12) + (w << 10)]);

    const f32x4 fzero = {0.f, 0.f, 0.f, 0.f};
    f32x4 acc[4][4];
    f32x4 rp[4] = {fzero, fzero, fzero, fzero};   // row partials, whole block

    #pragma unroll 1
    for (int jt = 0; jt < 16; ++jt) {
        const int col0 = ((jg << 4) + jt) << 7;
        #pragma unroll
        for (int kc = 0; kc < 4; ++kc) {
            __syncthreads();   // prior compute done with sB (A also drained, 1st iter)
            // stage B kc-block: wave w covers rows w*32..w*32+31, 2 rounds
            #pragma unroll
            for (int R = 0; R < 2; ++R) {
                const int rbase = (w << 5) + (R << 4);           // 16 rows per round
                const int r = rbase + (lane >> 2);
                gload16(B8 + ((size_t)(col0 + r) << 8) + (kc << 6) + ((lane & 3) << 4),
                        &sB[(rbase << 6) + ((size_t)lane << 4)]);
            }
            __syncthreads();   // drains vmcnt -> sB ready
            // ---- one b128 per operand row, two MFMAs per pair ----
            const int Lq = (kc << 2) | q;
            i64x2 af[4], bf[4];
            #pragma unroll
            for (int rb = 0; rb < 4; ++rb) {
                const int rr = (wr << 6) + (rb << 4) + m;
                const int PA = (Lq & 8) | ((Lq & 7) ^ (rr & 7));
                af[rb] = *(const i64x2*)(&sA[(rr << 8) + (PA << 4)]);
                const int cr = (wc << 6) + (rb << 4) + m;
                const int PB = q ^ ((cr >> 1) & 3);
                bf[rb] = *(const i64x2*)(&sB[(cr << 6) + (PB << 4)]);
            }
            if (kc == 0) {
                #pragma unroll
                for (int rb = 0; rb < 4; ++rb)
                    #pragma unroll
                    for (int cb = 0; cb < 4; ++cb)
                        acc[rb][cb] = __builtin_amdgcn_mfma_f32_16x16x32_fp8_fp8(
                            af[rb].x, bf[cb].x, fzero, 0, 0, 0);
            } else {
                #pragma unroll
                for (int rb = 0; rb < 4; ++rb)
                    #pragma unroll
                    for (int cb = 0; cb < 4; ++cb)
                        acc[rb][cb] = __builtin_amdgcn_mfma_f32_16x16x32_fp8_fp8(
                            af[rb].x, bf[cb].x, acc[rb][cb], 0, 0, 0);
            }
            #pragma unroll
            for (int rb = 0; rb < 4; ++rb)
                #pragma unroll
                for (int cb = 0; cb < 4; ++cb)
                    acc[rb][cb] = __builtin_amdgcn_mfma_f32_16x16x32_fp8_fp8(
                        af[rb].y, bf[cb].y, acc[rb][cb], 0, 0, 0);
        }

        // ---- per-tile epilogue (registers + global atomics only) ----
        // diag (pre-exp, log2-scaled): D layout col=m, row=q*4+r
        if (bi == ((jg << 4) + jt) && wr == wc) {
            #pragma unroll
            for (int rb = 0; rb < 4; ++rb)
                #pragma unroll
                for (int r = 0; r < 4; ++r)
                    if (m == ((q << 2) | r))
                        diag[row0 + (wr << 6) + (rb << 4) + m] = acc[rb][rb][r];
        }
        // exp2(l' - 144) in place
        #pragma unroll
        for (int rb = 0; rb < 4; ++rb)
            #pragma unroll
            for (int cb = 0; cb < 4; ++cb)
                #pragma unroll
                for (int r = 0; r < 4; ++r)
                    acc[rb][cb][r] = __builtin_amdgcn_exp2f(acc[rb][cb][r] - 144.0f);

        // row partials: pure VALU, reduced once at block end
        #pragma unroll
        for (int rb = 0; rb < 4; ++rb)
            rp[rb] += (acc[rb][0] + acc[rb][1]) + (acc[rb][2] + acc[rb][3]);

        // col partials: in-lane adds + 2 cross-quad shuffles; lane keeps cb==q
        float cpart = 0.0f;
        #pragma unroll
        for (int cb = 0; cb < 4; ++cb) {
            float v = 0.0f;
            #pragma unroll
            for (int rb = 0; rb < 4; ++rb)
                v += (acc[rb][cb][0] + acc[rb][cb][1]) + (acc[rb][cb][2] + acc[rb][cb][3]);
            v += __shfl_xor(v, 16, 64);
            v += __shfl_xor(v, 32, 64);
            if (q == cb) cpart = v;
        }
        atomicAdd(&s_col[col0 + (wc << 6) + (q << 4) + m], cpart);
    }

    // ---- block-end row reduction: rp[rb][r] is row (wr*64+rb*16+q*4+r),
    // distributed over the 16 m-lanes of quad q. Butterfly over m.
    float rout = 0.0f;
    #pragma unroll
    for (int rb = 0; rb < 4; ++rb)
        #pragma unroll
        for (int r = 0; r < 4; ++r) {
            float v = rp[rb][r];
            v += __shfl_xor(v, 1, 16);
            v += __shfl_xor(v, 2, 16);
            v += __shfl_xor(v, 4, 16);
            v += __shfl_xor(v, 8, 16);
            if (m == ((rb << 2) | r)) rout = v;
        }
    atomicAdd(&s_row[row0 + (wr << 6) + ((m >> 2) << 4) + (q << 2) + (m & 3)], rout);
}

// ---------- kernel 3: final reduce (64 blocks, 256 rows each) ----------
__global__ void final_kernel(const float* __restrict__ s_row, const float* __restrict__ s_col,
                             const float* __restrict__ diag, float* __restrict__ out) {
    __shared__ double red[256];
    int t = threadIdx.x;
    int i = blockIdx.x * 256 + t;
    double p = 0.5 * (double)(log2f(s_row[i]) + log2f(s_col[i])) + 144.0 - (double)diag[i];
    red[t] = p;
    __syncthreads();
    for (int s = 128; s > 0; s >>= 1) {
        if (t < s) red[t] += red[t + s];
        __syncthreads();
    }
    if (t == 0) atomicAdd(out, (float)(red[0] * 0.6931471805599453 / (double)NN));
}

// ---------- launch ----------
extern "C" void kernel_launch(void* const* d_in, const int* in_sizes, int n_in,
                              void* d_out, int out_size, void* d_ws, size_t ws_size,
                              hipStream_t stream) {
    const float* img = (const float*)d_in[0];
    const float* txt = (const float*)d_in[1];
    char* ws = (char*)d_ws;
    u8*    A8    = (u8*)ws;                                // 4 MB
    u8*    B8    = (u8*)(ws + 4194304);                    // 4 MB
    float* s_row = (float*)(ws + 8388608);                 // 64 KB
    float* s_col = (float*)(ws + 8388608 + 65536);         // 64 KB
    float* diag  = (float*)(ws + 8388608 + 131072);        // 64 KB
    float* out   = (float*)d_out;

    prep_kernel<<<4096, 256, 0, stream>>>(img, txt, A8, B8, s_row, out);
    gemm_lse_kernel<<<1024, 256, 0, stream>>>(A8, B8, s_row, s_col, diag);
    final_kernel<<<64, 256, 0, stream>>>(s_row, s_col, diag, out);
}

// Round 11
// 241.752 us; speedup vs baseline: 1.0510x; 1.0510x over previous
//
#include <hip/hip_runtime.h>
#include <hip/hip_bf16.h>

#define NN 16384
#define DD 256

typedef unsigned short u16;
typedef unsigned int u32;
typedef unsigned char u8;
typedef long i64;
typedef __attribute__((ext_vector_type(2))) long i64x2;
typedef __attribute__((ext_vector_type(4))) float f32x4;

// async global->LDS, 16B per lane; LDS dest = wave-uniform base + lane*16
static __device__ __forceinline__ void gload16(const u8* g, u8* l) {
    __builtin_amdgcn_global_load_lds(
        (const __attribute__((address_space(1))) void*)g,
        (__attribute__((address_space(3))) void*)l,
        16, 0, 0);
}

// ---------- kernel 1: convert to fp8 e4m3, PAIR-PACKED + XOR-swizzled (R10 layout) ----------
__global__ void prep_kernel(const float* __restrict__ img, const float* __restrict__ txt,
                            u8* __restrict__ A8, u8* __restrict__ B8,
                            float* __restrict__ s_row, float* __restrict__ out) {
    int gid = blockIdx.x * 256 + threadIdx.x;          // 0 .. 1048575  (N*D/4)
    float4 va = ((const float4*)img)[gid];
    float4 vb = ((const float4*)txt)[gid];
    const float S = 1.44269504088896f;                  // log2(e) folded into A
    int pa = __builtin_amdgcn_cvt_pk_fp8_f32(va.x * S, va.y * S, 0, false);
    pa     = __builtin_amdgcn_cvt_pk_fp8_f32(va.z * S, va.w * S, pa, true);
    int pb = __builtin_amdgcn_cvt_pk_fp8_f32(vb.x, vb.y, 0, false);
    pb     = __builtin_amdgcn_cvt_pk_fp8_f32(vb.z, vb.w, pb, true);

    const int r  = gid >> 6;
    const int ko = (gid & 63) << 2;     // k-byte offset 0..255, step 4
    const int J  = ko >> 3;             // 8-byte slot 0..31
    const int u  = ko & 7;              // 0 or 4
    const int kc = J >> 3;
    const int s  = (J >> 2) & 1;
    const int qq = J & 3;
    // A: 16B chunk L=kc*4+q (s0|s1 halves adjacent) at P=(L&8)|((L&7)^(r&7))
    {
        const int L  = (kc << 2) | qq;
        const int P  = (L & 8) | ((L & 7) ^ (r & 7));
        *(u32*)(A8 + ((size_t)r << 8) + (P << 4) + (s << 3) + u) = (u32)pa;
    }
    // B: per-kc 64B block, chunk q at P=q^((r>>1)&3)
    {
        const int P  = qq ^ ((r >> 1) & 3);
        *(u32*)(B8 + ((size_t)r << 8) + (kc << 6) + (P << 4) + (s << 3) + u) = (u32)pb;
    }
    if (gid < 16384) s_row[gid] = 0.0f;
    if (gid == 0) out[0] = 0.0f;
}

// ---------- kernel 2: fused fp8 GEMM + exp2 + row/col sum + diag ----------
// R10 base EXACTLY (A-once 32 KB LDS, 8 KB B per kc, 2 barriers/kc, b128
// pair-packed reads, 4 blocks/CU, bi-fast grid). ONE change: col sums no
// longer use global atomics (R10: 4.19M atomicAdds -> 233 MB of HBM line
// ping-pong across non-coherent XCD L2s). Instead each block writes PLAIN
// stores to its private slab part[bi][col]; the two wr-waves sharing a column
// combine via a 512 B scratch in the (dead-between-tiles) sB buffer.
// final_kernel does the 128-way column reduction.
__global__ __launch_bounds__(256, 4) void gemm_lse_kernel(
        const u8* __restrict__ A8, const u8* __restrict__ B8,
        float* __restrict__ part, float* __restrict__ s_row,
        float* __restrict__ diag) {
    __shared__ u8 sA[32768];        // 128 rows x 256 B (pre-swizzled)
    __shared__ u8 sB[8192];         // 128 rows x 64 B  (pre-swizzled, per kc) + epilogue scratch

    const int t = threadIdx.x;
    const int lane = t & 63;
    const int w = t >> 6;
    const int wr = w >> 1, wc = w & 1;
    const int q = lane >> 4, m = lane & 15;
    const int bi = blockIdx.x & 127;            // FAST: resident blocks share B phase
    const int jg = blockIdx.x >> 7;
    const int row0 = bi << 7;

    // ---- stage A panel ONCE: linear 32 KB copy, 8 rounds x 256 lanes x 16 B
    #pragma unroll
    for (int R = 0; R < 8; ++R)
        gload16(A8 + ((size_t)row0 << 8) + (R << 12) + (w << 10) + ((size_t)lane << 4),
                &sA[(R << 12) + (w << 10)]);

    const f32x4 fzero = {0.f, 0.f, 0.f, 0.f};
    f32x4 acc[4][4];
    f32x4 rp[4] = {fzero, fzero, fzero, fzero};   // row partials, whole block

    #pragma unroll 1
    for (int jt = 0; jt < 16; ++jt) {
        const int col0 = ((jg << 4) + jt) << 7;
        #pragma unroll
        for (int kc = 0; kc < 4; ++kc) {
            __syncthreads();   // prior compute/epilogue done with sB (A drained, 1st iter)
            // stage B kc-block: wave w covers rows w*32..w*32+31, 2 rounds
            #pragma unroll
            for (int R = 0; R < 2; ++R) {
                const int rbase = (w << 5) + (R << 4);           // 16 rows per round
                const int r = rbase + (lane >> 2);
                gload16(B8 + ((size_t)(col0 + r) << 8) + (kc << 6) + ((lane & 3) << 4),
                        &sB[(rbase << 6) + ((size_t)lane << 4)]);
            }
            __syncthreads();   // drains vmcnt -> sB ready
            // ---- one b128 per operand row, two MFMAs per pair ----
            const int Lq = (kc << 2) | q;
            i64x2 af[4], bf[4];
            #pragma unroll
            for (int rb = 0; rb < 4; ++rb) {
                const int rr = (wr << 6) + (rb << 4) + m;
                const int PA = (Lq & 8) | ((Lq & 7) ^ (rr & 7));
                af[rb] = *(const i64x2*)(&sA[(rr << 8) + (PA << 4)]);
                const int cr = (wc << 6) + (rb << 4) + m;
                const int PB = q ^ ((cr >> 1) & 3);
                bf[rb] = *(const i64x2*)(&sB[(cr << 6) + (PB << 4)]);
            }
            if (kc == 0) {
                #pragma unroll
                for (int rb = 0; rb < 4; ++rb)
                    #pragma unroll
                    for (int cb = 0; cb < 4; ++cb)
                        acc[rb][cb] = __builtin_amdgcn_mfma_f32_16x16x32_fp8_fp8(
                            af[rb].x, bf[cb].x, fzero, 0, 0, 0);
            } else {
                #pragma unroll
                for (int rb = 0; rb < 4; ++rb)
                    #pragma unroll
                    for (int cb = 0; cb < 4; ++cb)
                        acc[rb][cb] = __builtin_amdgcn_mfma_f32_16x16x32_fp8_fp8(
                            af[rb].x, bf[cb].x, acc[rb][cb], 0, 0, 0);
            }
            #pragma unroll
            for (int rb = 0; rb < 4; ++rb)
                #pragma unroll
                for (int cb = 0; cb < 4; ++cb)
                    acc[rb][cb] = __builtin_amdgcn_mfma_f32_16x16x32_fp8_fp8(
                        af[rb].y, bf[cb].y, acc[rb][cb], 0, 0, 0);
        }

        // ---- per-tile epilogue ----
        // diag (pre-exp, log2-scaled): D layout col=m, row=q*4+r
        if (bi == ((jg << 4) + jt) && wr == wc) {
            #pragma unroll
            for (int rb = 0; rb < 4; ++rb)
                #pragma unroll
                for (int r = 0; r < 4; ++r)
                    if (m == ((q << 2) | r))
                        diag[row0 + (wr << 6) + (rb << 4) + m] = acc[rb][rb][r];
        }
        // exp2(l' - 144) in place
        #pragma unroll
        for (int rb = 0; rb < 4; ++rb)
            #pragma unroll
            for (int cb = 0; cb < 4; ++cb)
                #pragma unroll
                for (int r = 0; r < 4; ++r)
                    acc[rb][cb][r] = __builtin_amdgcn_exp2f(acc[rb][cb][r] - 144.0f);

        // row partials: pure VALU, reduced once at block end
        #pragma unroll
        for (int rb = 0; rb < 4; ++rb)
            rp[rb] += (acc[rb][0] + acc[rb][1]) + (acc[rb][2] + acc[rb][3]);

        // col partials: in-lane adds + 2 cross-quad shuffles; every lane ends
        // with cpart for col = col0 + wc*64 + q*16 + m (cb == q kept).
        float cpart = 0.0f;
        #pragma unroll
        for (int cb = 0; cb < 4; ++cb) {
            float v = 0.0f;
            #pragma unroll
            for (int rb = 0; rb < 4; ++rb)
                v += (acc[rb][cb][0] + acc[rb][cb][1]) + (acc[rb][cb][2] + acc[rb][cb][3]);
            v += __shfl_xor(v, 16, 64);
            v += __shfl_xor(v, 32, 64);
            if (q == cb) cpart = v;
        }
        // combine the two wr-waves of each wc through LDS scratch (sB is dead
        // between tiles), then ONE plain coalesced store per column. No atomics.
        __syncthreads();                       // all waves done reading sB
        float* scr = (float*)sB;
        const int ci = (wc << 6) + (q << 4) + m;
        if (wr == 0) scr[ci] = cpart;
        __syncthreads();
        if (wr == 1)
            part[((size_t)bi << 14) + col0 + ci] = cpart + scr[ci];
        // (next kc-loop iteration's first barrier protects scr until read)
    }

    // ---- block-end row reduction: rp[rb][r] is row (wr*64+rb*16+q*4+r),
    // distributed over the 16 m-lanes of quad q. Butterfly over m.
    float rout = 0.0f;
    #pragma unroll
    for (int rb = 0; rb < 4; ++rb)
        #pragma unroll
        for (int r = 0; r < 4; ++r) {
            float v = rp[rb][r];
            v += __shfl_xor(v, 1, 16);
            v += __shfl_xor(v, 2, 16);
            v += __shfl_xor(v, 4, 16);
            v += __shfl_xor(v, 8, 16);
            if (m == ((rb << 2) | r)) rout = v;
        }
    atomicAdd(&s_row[row0 + (wr << 6) + ((m >> 2) << 4) + (q << 2) + (m & 3)], rout);
}

// ---------- kernel 3: final reduce ----------
// 16 blocks x 256 threads; each thread owns 4 columns (float4): 128-way
// partial-sum over part (128 independent 16 B loads), then the loss terms.
__global__ void final_kernel(const float4* __restrict__ part4,
                             const float4* __restrict__ s_row4,
                             const float4* __restrict__ diag4,
                             float* __restrict__ out) {
    __shared__ double red[256];
    const int t = threadIdx.x;
    const int g = blockIdx.x * 256 + t;        // 0..4095, cols 4g..4g+3
    float4 cs = {0.f, 0.f, 0.f, 0.f};
    #pragma unroll 8
    for (int b = 0; b < 128; ++b) {
        float4 v = part4[b * 4096 + g];
        cs.x += v.x; cs.y += v.y; cs.z += v.z; cs.w += v.w;
    }
    float4 sr = s_row4[g];
    float4 dg = diag4[g];
    double p = 0.0;
    p += 0.5 * (double)(log2f(sr.x) + log2f(cs.x)) + 144.0 - (double)dg.x;
    p += 0.5 * (double)(log2f(sr.y) + log2f(cs.y)) + 144.0 - (double)dg.y;
    p += 0.5 * (double)(log2f(sr.z) + log2f(cs.z)) + 144.0 - (double)dg.z;
    p += 0.5 * (double)(log2f(sr.w) + log2f(cs.w)) + 144.0 - (double)dg.w;
    red[t] = p;
    __syncthreads();
    for (int s = 128; s > 0; s >>= 1) {
        if (t < s) red[t] += red[t + s];
        __syncthreads();
    }
    if (t == 0) atomicAdd(out, (float)(red[0] * 0.6931471805599453 / (double)NN));
}

// ---------- launch ----------
extern "C" void kernel_launch(void* const* d_in, const int* in_sizes, int n_in,
                              void* d_out, int out_size, void* d_ws, size_t ws_size,
                              hipStream_t stream) {
    const float* img = (const float*)d_in[0];
    const float* txt = (const float*)d_in[1];
    char* ws = (char*)d_ws;
    u8*    A8    = (u8*)ws;                                // 4 MB
    u8*    B8    = (u8*)(ws + 4194304);                    // 4 MB
    float* part  = (float*)(ws + 8388608);                 // 8 MB (128 x 16384)
    float* s_row = (float*)(ws + 16777216);                // 64 KB
    float* diag  = (float*)(ws + 16777216 + 65536);        // 64 KB
    float* out   = (float*)d_out;

    prep_kernel<<<4096, 256, 0, stream>>>(img, txt, A8, B8, s_row, out);
    gemm_lse_kernel<<<1024, 256, 0, stream>>>(A8, B8, part, s_row, diag);
    final_kernel<<<16, 256, 0, stream>>>((const float4*)part, (const float4*)s_row,
                                         (const float4*)diag, out);
}

// Round 12
// 197.660 us; speedup vs baseline: 1.2854x; 1.2231x over previous
//
#include <hip/hip_runtime.h>
#include <hip/hip_bf16.h>

#define NN 16384
#define DD 256

typedef unsigned short u16;
typedef unsigned int u32;
typedef unsigned char u8;
typedef long i64;
typedef __attribute__((ext_vector_type(4))) float f32x4;

// async global->LDS, 16B per lane; LDS dest = wave-uniform base + lane*16
static __device__ __forceinline__ void gload16(const u8* g, u8* l) {
    __builtin_amdgcn_global_load_lds(
        (const __attribute__((address_space(1))) void*)g,
        (__attribute__((address_space(3))) void*)l,
        16, 0, 0);
}

// ---------- kernel 1: fp8 e4m3 convert, pre-swizzled into bank-exact layouts ----------
// A8: [bi][kc][rl 0..127][64 B rows]. chunk cs=(s<<1)|(qq>>1) at P=cs^((rl^(rl>>2))&3),
//     8B half qq&1 at h=(qq&1)^((rl>>3)&1).
// B8: [cb][rl 0..127][256 B rows]. kc-block at kc^((rl>>1)&3); chunk cs at
//     P=cs^((((rl>>2)&1)<<1)|(rl&1)); half at (qq&1 -> s? no:) h=(qq&1)^((rl>>3)&1).
// Derivation (full 16-lane enumeration, all parity sets): each quad's 16 lanes x
// 2 dwords of a ds_read_b64 cover all 32 banks exactly once -> 4-phase minimum.
__global__ void prep_kernel(const float* __restrict__ img, const float* __restrict__ txt,
                            u8* __restrict__ A8, u8* __restrict__ B8,
                            float* __restrict__ zbuf /* s_row..s_col 32768 f */,
                            float* __restrict__ out) {
    int gid = blockIdx.x * 256 + threadIdx.x;          // 0 .. 1048575  (N*D/4)
    float4 va = ((const float4*)img)[gid];
    float4 vb = ((const float4*)txt)[gid];
    const float S = 1.44269504088896f;                  // log2(e) folded into A
    int pa = __builtin_amdgcn_cvt_pk_fp8_f32(va.x * S, va.y * S, 0, false);
    pa     = __builtin_amdgcn_cvt_pk_fp8_f32(va.z * S, va.w * S, pa, true);
    int pb = __builtin_amdgcn_cvt_pk_fp8_f32(vb.x, vb.y, 0, false);
    pb     = __builtin_amdgcn_cvt_pk_fp8_f32(vb.z, vb.w, pb, true);

    const int r  = gid >> 6;            // global row
    const int rl = r & 127;             // row within 128-panel
    const int pn = r >> 7;              // panel (bi / cb)
    const int ko = (gid & 63) << 2;     // k-byte offset 0..255, step 4
    const int J  = ko >> 3;             // 8-byte slot 0..31
    const int u  = ko & 7;              // 0 or 4
    const int kc = J >> 3;
    const int s  = (J >> 2) & 1;
    const int qq = J & 3;
    const int cs = (s << 1) | (qq >> 1);
    const int hh = (qq & 1) ^ ((rl >> 3) & 1);
    // A
    {
        const int P = cs ^ ((rl ^ (rl >> 2)) & 3);
        *(u32*)(A8 + ((size_t)pn << 15) + (kc << 13) + (rl << 6)
                   + (P << 4) + (hh << 3) + u) = (u32)pa;
    }
    // B
    {
        const int kp = kc ^ ((rl >> 1) & 3);
        const int P  = cs ^ (((( rl >> 2) & 1) << 1) | (rl & 1));
        *(u32*)(B8 + ((size_t)pn << 15) + (rl << 8) + (kp << 6)
                   + (P << 4) + (hh << 3) + u) = (u32)pb;
    }
    if (gid < 32768) zbuf[gid] = 0.0f;
    if (gid == 0) out[0] = 0.0f;
}

// ---------- kernel 2: fused fp8 GEMM + exp2 + row/col sum + diag ----------
// vs R8 (best measured, 140 us, MfmaUtil 40%): (1) WHOLE 32 KB B tile staged per
// jt -> 2 barriers/tile (17 pairs/block vs 65): 256 MFMAs/wave between barriers,
// attacking the lock-step vmcnt(0) drains that ate ~50% of R8's wall.
// (2) bank-exact b64 layout (R8 measured +4 cyc/b64 = 2x LDS penalty -> 0).
// LDS 64 KB -> 2 blocks/CU, grid = 2 generations (natural drain stagger).
// Epilogue/reductions: R8's exact measured-clean form (WRITE 29.7 MB).
__global__ __launch_bounds__(256, 2) void gemm_lse_kernel(
        const u8* __restrict__ A8, const u8* __restrict__ B8,
        float* __restrict__ s_row, float* __restrict__ s_col,
        float* __restrict__ diag) {
    __shared__ u8 sA[32768];        // [kc][128 rows][64 B]  (pre-swizzled)
    __shared__ u8 sB[32768];        // [128 rows][256 B]     (pre-swizzled)

    const int t = threadIdx.x;
    const int lane = t & 63;
    const int w = t >> 6;
    const int wr = w >> 1, wc = w & 1;
    const int q = lane >> 4, m = lane & 15;
    const int bi = blockIdx.x & 127;            // FAST: resident blocks share B phase
    const int jg = blockIdx.x >> 7;
    const int row0 = bi << 7;

    // ---- stage A panel ONCE: linear 32 KB copy, 8 rounds x 256 lanes x 16 B
    #pragma unroll
    for (int R = 0; R < 8; ++R)
        gload16(A8 + ((size_t)bi << 15) + (R << 12) + (w << 10) + ((size_t)lane << 4),
                &sA[(R << 12) + (w << 10)]);

    const f32x4 fzero = {0.f, 0.f, 0.f, 0.f};
    f32x4 acc[4][4];
    f32x4 rp[4] = {fzero, fzero, fzero, fzero};   // row partials, whole block

    #pragma unroll 1
    for (int jt = 0; jt < 16; ++jt) {
        const int ct = (jg << 4) + jt;            // column tile index
        const int col0 = ct << 7;
        __syncthreads();   // all waves done computing previous tile from sB
        #pragma unroll
        for (int R = 0; R < 8; ++R)
            gload16(B8 + ((size_t)ct << 15) + (R << 12) + (w << 10) + ((size_t)lane << 4),
                    &sB[(R << 12) + (w << 10)]);
        __syncthreads();   // drains vmcnt -> sB (and sA on jt=0) ready

        // ---- 256 MFMAs per wave, no barriers inside ----
        #pragma unroll
        for (int kc = 0; kc < 4; ++kc) {
            #pragma unroll
            for (int s = 0; s < 2; ++s) {
                const int cs = (s << 1) | (q >> 1);
                i64 af[4], bf[4];
                #pragma unroll
                for (int rb = 0; rb < 4; ++rb) {
                    const int rr = (wr << 6) + (rb << 4) + m;
                    const int PA = cs ^ ((rr ^ (rr >> 2)) & 3);
                    const int hA = (q & 1) ^ ((rr >> 3) & 1);
                    af[rb] = *(const i64*)(&sA[(kc << 13) + (rr << 6) + (PA << 4) + (hA << 3)]);
                    const int cr = (wc << 6) + (rb << 4) + m;
                    const int kp = kc ^ ((cr >> 1) & 3);
                    const int PB = cs ^ ((((cr >> 2) & 1) << 1) | (cr & 1));
                    const int hB = (q & 1) ^ ((cr >> 3) & 1);
                    bf[rb] = *(const i64*)(&sB[(cr << 8) + (kp << 6) + (PB << 4) + (hB << 3)]);
                }
                if (kc == 0 && s == 0) {
                    #pragma unroll
                    for (int rb = 0; rb < 4; ++rb)
                        #pragma unroll
                        for (int cb = 0; cb < 4; ++cb)
                            acc[rb][cb] = __builtin_amdgcn_mfma_f32_16x16x32_fp8_fp8(
                                af[rb], bf[cb], fzero, 0, 0, 0);
                } else {
                    #pragma unroll
                    for (int rb = 0; rb < 4; ++rb)
                        #pragma unroll
                        for (int cb = 0; cb < 4; ++cb)
                            acc[rb][cb] = __builtin_amdgcn_mfma_f32_16x16x32_fp8_fp8(
                                af[rb], bf[cb], acc[rb][cb], 0, 0, 0);
                }
            }
        }

        // ---- per-tile epilogue (R8's exact form) ----
        if (bi == ct && wr == wc) {
            #pragma unroll
            for (int rb = 0; rb < 4; ++rb)
                #pragma unroll
                for (int r = 0; r < 4; ++r)
                    if (m == ((q << 2) | r))
                        diag[row0 + (wr << 6) + (rb << 4) + m] = acc[rb][rb][r];
        }
        #pragma unroll
        for (int rb = 0; rb < 4; ++rb)
            #pragma unroll
            for (int cb = 0; cb < 4; ++cb)
                #pragma unroll
                for (int r = 0; r < 4; ++r)
                    acc[rb][cb][r] = __builtin_amdgcn_exp2f(acc[rb][cb][r] - 144.0f);

        #pragma unroll
        for (int rb = 0; rb < 4; ++rb)
            rp[rb] += (acc[rb][0] + acc[rb][1]) + (acc[rb][2] + acc[rb][3]);

        float cpart = 0.0f;
        #pragma unroll
        for (int cb = 0; cb < 4; ++cb) {
            float v = 0.0f;
            #pragma unroll
            for (int rb = 0; rb < 4; ++rb)
                v += (acc[rb][cb][0] + acc[rb][cb][1]) + (acc[rb][cb][2] + acc[rb][cb][3]);
            v += __shfl_xor(v, 16, 64);
            v += __shfl_xor(v, 32, 64);
            if (q == cb) cpart = v;
        }
        atomicAdd(&s_col[col0 + (wc << 6) + (q << 4) + m], cpart);
    }

    // ---- block-end row reduction ----
    float rout = 0.0f;
    #pragma unroll
    for (int rb = 0; rb < 4; ++rb)
        #pragma unroll
        for (int r = 0; r < 4; ++r) {
            float v = rp[rb][r];
            v += __shfl_xor(v, 1, 16);
            v += __shfl_xor(v, 2, 16);
            v += __shfl_xor(v, 4, 16);
            v += __shfl_xor(v, 8, 16);
            if (m == ((rb << 2) | r)) rout = v;
        }
    atomicAdd(&s_row[row0 + (wr << 6) + ((m >> 2) << 4) + (q << 2) + (m & 3)], rout);
}

// ---------- kernel 3: final reduce (64 blocks, 256 rows each) ----------
__global__ void final_kernel(const float* __restrict__ s_row, const float* __restrict__ s_col,
                             const float* __restrict__ diag, float* __restrict__ out) {
    __shared__ double red[256];
    int t = threadIdx.x;
    int i = blockIdx.x * 256 + t;
    double p = 0.5 * (double)(log2f(s_row[i]) + log2f(s_col[i])) + 144.0 - (double)diag[i];
    red[t] = p;
    __syncthreads();
    for (int s = 128; s > 0; s >>= 1) {
        if (t < s) red[t] += red[t + s];
        __syncthreads();
    }
    if (t == 0) atomicAdd(out, (float)(red[0] * 0.6931471805599453 / (double)NN));
}

// ---------- launch ----------
extern "C" void kernel_launch(void* const* d_in, const int* in_sizes, int n_in,
                              void* d_out, int out_size, void* d_ws, size_t ws_size,
                              hipStream_t stream) {
    const float* img = (const float*)d_in[0];
    const float* txt = (const float*)d_in[1];
    char* ws = (char*)d_ws;
    u8*    A8    = (u8*)ws;                                // 4 MB
    u8*    B8    = (u8*)(ws + 4194304);                    // 4 MB
    float* s_row = (float*)(ws + 8388608);                 // 64 KB
    float* s_col = (float*)(ws + 8388608 + 65536);         // 64 KB
    float* diag  = (float*)(ws + 8388608 + 131072);        // 64 KB
    float* out   = (float*)d_out;

    prep_kernel<<<4096, 256, 0, stream>>>(img, txt, A8, B8, s_row, out);
    gemm_lse_kernel<<<1024, 256, 0, stream>>>(A8, B8, s_row, s_col, diag);
    final_kernel<<<64, 256, 0, stream>>>(s_row, s_col, diag, out);
}